// Round 11
// baseline (298.791 us; speedup 1.0000x reference)
//
#include <hip/hip_runtime.h>
#include <hip/hip_bf16.h>

#define B_   4
#define LQ_  4096
#define LS_  4096
#define DH_  1024
#define BQ_  64
#define BS_  256
#define NT_  (LS_/BS_)   /* 16 */
#define NTH  512

typedef __bf16 bf16x8 __attribute__((ext_vector_type(8)));
typedef float  f32x4  __attribute__((ext_vector_type(4)));
typedef float  f32x16 __attribute__((ext_vector_type(16)));
typedef unsigned char u8;

#define WAITL()  asm volatile("s_waitcnt lgkmcnt(0)" ::: "memory")
#define BAR()    __builtin_amdgcn_s_barrier()

__device__ __forceinline__ unsigned short f2bf(float f) {
  union { __bf16 h; unsigned short u; } cv;
  cv.h = (__bf16)f;
  return cv.u;
}
__device__ __forceinline__ bf16x8 cvt8(f32x4 a, f32x4 b) {
  bf16x8 r;
  r[0] = (__bf16)a[0]; r[1] = (__bf16)a[1]; r[2] = (__bf16)a[2]; r[3] = (__bf16)a[3];
  r[4] = (__bf16)b[0]; r[5] = (__bf16)b[1]; r[6] = (__bf16)b[2]; r[7] = (__bf16)b[3];
  return r;
}

// ---- fp32 S -> fragment-major bf16 layouts (wave-contiguous 1KB ring loads) ----
__global__ __launch_bounds__(256) void cvt_kernel(const float* __restrict__ S,
                                                  u8* __restrict__ Kf,
                                                  u8* __restrict__ Vf)
{
  __shared__ unsigned short tile[64][72];
  const int b  = blockIdx.z;
  const int dt = blockIdx.y;   // 0..15  (64 d each)
  const int st = blockIdx.x;   // 0..63  (64 s each)
  const int tid = threadIdx.x;
  const int t  = st >> 2;
  const float* Sbase = S + ((size_t)b*LS_ + (size_t)st*64)*DH_ + dt*64;

  #pragma unroll
  for (int k = 0; k < 4; ++k) {
    int fi  = tid + k*256;
    int row = fi >> 4;
    int c4  = fi & 15;
    float4 v = *reinterpret_cast<const float4*>(Sbase + (size_t)row*DH_ + c4*4);
    ushort4 h;
    h.x = f2bf(v.x); h.y = f2bf(v.y); h.z = f2bf(v.z); h.w = f2bf(v.w);
    *reinterpret_cast<ushort4*>(&tile[row][c4*4]) = h;
  }
  __syncthreads();

  // Kf: 8x 1KB blocks
  #pragma unroll
  for (int h2 = 0; h2 < 2; ++h2) {
    int u    = tid + h2*256;
    int blk  = u >> 6;
    int wloc = blk >> 2;
    int kkl  = blk & 3;
    int lane = u & 63;
    int sh   = lane >> 5, sl = lane & 31;
    int srow = wloc*32 + sl;
    int scol = kkl*16 + sh*8;
    ushort4 h0 = *reinterpret_cast<const ushort4*>(&tile[srow][scol]);
    ushort4 h1 = *reinterpret_cast<const ushort4*>(&tile[srow][scol+4]);
    int w_g  = (st & 3)*2 + wloc;
    int kk_g = dt*4 + kkl;
    u8* dst = Kf + (size_t)(((b*16 + t)*8 + w_g)*64 + kk_g)*1024 + lane*16;
    *reinterpret_cast<ushort4*>(dst)     = h0;
    *reinterpret_cast<ushort4*>(dst + 8) = h1;
  }

  // Vf: 8x 1KB blocks (transposed gather)
  #pragma unroll
  for (int h2 = 0; h2 < 2; ++h2) {
    int u    = tid + h2*256;
    int blk  = u >> 6;
    int ksl  = blk >> 2;
    int nfl  = blk & 3;
    int lane = u & 63;
    int lg   = lane >> 4, lr = lane & 15;
    int srow = ksl*32 + lg*8;
    int dcol = nfl*16 + lr;
    ushort4 h0, h1;
    h0.x = tile[srow+0][dcol]; h0.y = tile[srow+1][dcol];
    h0.z = tile[srow+2][dcol]; h0.w = tile[srow+3][dcol];
    h1.x = tile[srow+4][dcol]; h1.y = tile[srow+5][dcol];
    h1.z = tile[srow+6][dcol]; h1.w = tile[srow+7][dcol];
    int w_g = dt >> 1;
    int i_g = ((st & 3)*2 + ksl)*8 + (dt & 1)*4 + nfl;
    u8* dst = Vf + (size_t)(((b*16 + t)*8 + w_g)*64 + i_g)*1024 + lane*16;
    *reinterpret_cast<ushort4*>(dst)     = h0;
    *reinterpret_cast<ushort4*>(dst + 8) = h1;
  }
}

// ---------------- fused flash attention, m==0 softmax, cross-tile pipelined ----------------
// Per-block rotated segment order de-hotspots L2 (commutative accumulation);
// rings distance 4 uniform; setprio around the 6-MFMA cluster; l via
// per-wave-distributed ones-MFMA.
__global__ __launch_bounds__(NTH, 1) void attn_kernel(
    const float* __restrict__ Qg,
    const u8* __restrict__ Kf,
    const u8* __restrict__ Vf,
    float* __restrict__ Og)
{
  __shared__ __align__(16) unsigned char qlds[131072];  // [qf:2][kk:64][lane:64]*16B
  __shared__ __align__(16) unsigned char plds[32768];   // P [64 q][256 s] bf16 swizzled

  const int tid = threadIdx.x;
  const int w  = tid >> 6;
  const int l  = tid & 63;
  const int lg = l >> 4;
  const int lr = l & 15;
  const int sl = l & 31;
  const int sh = l >> 5;

  const int n    = blockIdx.x;
  const int xcd  = n & 7;
  const int slot = n >> 3;
  const int b    = xcd >> 1;
  const int qt   = (xcd & 1)*32 + slot;
  const int off  = slot & 7;            // rotation offset in segments

  const float* Qbase = Qg + ((size_t)b*LQ_ + (size_t)qt*BQ_)*DH_;
  const u8* kptr = Kf + (size_t)b*8388608 + (size_t)w*65536 + l*16;
  const u8* vptr = Vf + (size_t)b*8388608 + (size_t)w*65536 + l*16;

  bf16x8 bk[4], bv[4];
  auto ldU = [&](const u8* base, int unit) -> bf16x8 {
    return *reinterpret_cast<const bf16x8*>(base + unit*1024);
  };
  auto ldP = [&](int mq, int ks) -> bf16x8 {
    int q = mq*16 + lr;
    return *reinterpret_cast<const bf16x8*>(
        plds + q*512 + ((ks*64 + lg*16) ^ ((q & 7) << 4)));
  };
  auto ldA = [&](int kk, int qf) -> bf16x8 {
    return *reinterpret_cast<const bf16x8*>(qlds + qf*65536 + kk*1024 + l*16);
  };

  // K-ring init for t=0: units off*8 + 0..3 (in flight across Q staging)
  bk[0] = ldU(kptr, off*8 + 0); bk[1] = ldU(kptr, off*8 + 1);
  bk[2] = ldU(kptr, off*8 + 2); bk[3] = ldU(kptr, off*8 + 3);

  // ---- stage Q fp32 -> bf16 into lane-linear fragment layout (once) ----
  #pragma unroll
  for (int it = 0; it < 16; ++it) {
    int u  = tid + it*NTH;
    int qf = u >> 12;
    int kk = (u >> 6) & 63;
    int ll = u & 63;
    int q  = qf*32 + (ll & 31);
    int d  = kk*16 + (ll >> 5)*8;
    const float* p = Qbase + (size_t)q*DH_ + d;
    f32x4 v0 = *reinterpret_cast<const f32x4*>(p);
    f32x4 v1 = *reinterpret_cast<const f32x4*>(p + 4);
    *reinterpret_cast<bf16x8*>(qlds + (size_t)u*16) = cvt8(v0, v1);
  }

  f32x4 Oacc[4][8];
  #pragma unroll
  for (int i = 0; i < 4; ++i)
    #pragma unroll
    for (int j = 0; j < 8; ++j)
      Oacc[i][j] = (f32x4){0.f, 0.f, 0.f, 0.f};
  f32x4 lacc[4];
  #pragma unroll
  for (int i = 0; i < 4; ++i) lacc[i] = (f32x4){0.f, 0.f, 0.f, 0.f};

  bf16x8 ones;
  #pragma unroll
  for (int e = 0; e < 8; ++e) ones[e] = (__bf16)1.0f;

  f32x16 qk0, qk1;
  const float SCL = 0.04508422f;   // (1/32) * log2(e)

  WAITL();
  BAR();   // Q staged (K-ring loads stay in flight)

  bf16x8 aqA0 = ldA(off*8, 0);
  bf16x8 aqA1 = ldA(off*8, 1);

  // ================= QK-only prologue: tile 0 (rotated segments) =================
  #pragma unroll
  for (int r = 0; r < 16; ++r) { qk0[r] = 0.f; qk1[r] = 0.f; }
  #pragma unroll 1
  for (int seg = 0; seg < 8; ++seg) {
    const int ibe = (seg + off) & 7;
    const int ibn = (ibe + 1) & 7;
    const u8* kP = (seg < 7) ? kptr : kptr + 524288;   // K(0) / K(1)
    #pragma unroll
    for (int j = 0; j < 8; ++j) {
      const int nu = (j < 7) ? (ibe*8 + j + 1) : (ibn*8);
      bf16x8 aqN0 = ldA(nu, 0);
      bf16x8 aqN1 = ldA(nu, 1);
      __builtin_amdgcn_s_setprio(1);
      qk0 = __builtin_amdgcn_mfma_f32_32x32x16_bf16(aqA0, bk[j & 3], qk0, 0, 0, 0);
      qk1 = __builtin_amdgcn_mfma_f32_32x32x16_bf16(aqA1, bk[j & 3], qk1, 0, 0, 0);
      __builtin_amdgcn_s_setprio(0);
      if (j < 4) bk[j] = ldU(kptr, ibe*8 + j + 4);
      else {
        bk[j - 4] = ldU(kP, ibn*8 + j - 4);
        if (seg == 7) bv[j - 4] = ldU(vptr, ibn*8 + j - 4);   // V(0) ring init (ibn==off)
      }
      aqA0 = aqN0; aqA1 = aqN1;
    }
  }

  // ================= main: t = 1..15, fused QK(t) + PV(t-1) =================
  #pragma unroll 1
  for (int t = 1; t < NT_; ++t) {
    BAR();   // all waves' plds reads of P(t-2) done

    // softmax(t-1): P = exp2(scl*logit) -> plds
    #pragma unroll
    for (int r = 0; r < 16; ++r) {
      int qrow = (r & 3) + 8*(r >> 2) + 4*sh;
      int s    = w*32 + sl;
      {
        float p = exp2f(qk0[r] * SCL);
        int q = qrow;
        *reinterpret_cast<__bf16*>(plds + q*512 + ((s*2) ^ ((q & 7) << 4))) = (__bf16)p;
      }
      {
        float p = exp2f(qk1[r] * SCL);
        int q = 32 + qrow;
        *reinterpret_cast<__bf16*>(plds + q*512 + ((s*2) ^ ((q & 7) << 4))) = (__bf16)p;
      }
    }
    WAITL();
    BAR();   // P(t-1) visible

    #pragma unroll
    for (int r = 0; r < 16; ++r) { qk0[r] = 0.f; qk1[r] = 0.f; }

    const u8* kT = kptr + (size_t)t*524288;
    const u8* vT = vptr + (size_t)(t-1)*524288;
    bf16x8 pa0, pa1, pa2, pa3;

    #pragma unroll 1
    for (int seg = 0; seg < 8; ++seg) {
      const int ibe = (seg + off) & 7;
      const int ibn = (ibe + 1) & 7;
      const u8* kP = (seg < 7) ? kT : kT + 524288;   // K(t) / K(t+1)
      const u8* vP = (seg < 7) ? vT : vT + 524288;   // V(t-1) / V(t)
      #pragma unroll
      for (int j = 0; j < 8; ++j) {
        const int nu = (j < 7) ? (ibe*8 + j + 1) : (ibn*8);
        bf16x8 aqN0 = ldA(nu, 0);
        bf16x8 aqN1 = ldA(nu, 1);
        if (j == 0) {
          pa0 = ldP(0, ibe); pa1 = ldP(1, ibe); pa2 = ldP(2, ibe); pa3 = ldP(3, ibe);
          if (ibe == w) {
            lacc[0] = __builtin_amdgcn_mfma_f32_16x16x32_bf16(pa0, ones, lacc[0], 0, 0, 0);
            lacc[1] = __builtin_amdgcn_mfma_f32_16x16x32_bf16(pa1, ones, lacc[1], 0, 0, 0);
            lacc[2] = __builtin_amdgcn_mfma_f32_16x16x32_bf16(pa2, ones, lacc[2], 0, 0, 0);
            lacc[3] = __builtin_amdgcn_mfma_f32_16x16x32_bf16(pa3, ones, lacc[3], 0, 0, 0);
          }
        }
        __builtin_amdgcn_s_setprio(1);
        qk0 = __builtin_amdgcn_mfma_f32_32x32x16_bf16(aqA0, bk[j & 3], qk0, 0, 0, 0);
        qk1 = __builtin_amdgcn_mfma_f32_32x32x16_bf16(aqA1, bk[j & 3], qk1, 0, 0, 0);
        Oacc[0][j] = __builtin_amdgcn_mfma_f32_16x16x32_bf16(pa0, bv[j & 3], Oacc[0][j], 0, 0, 0);
        Oacc[1][j] = __builtin_amdgcn_mfma_f32_16x16x32_bf16(pa1, bv[j & 3], Oacc[1][j], 0, 0, 0);
        Oacc[2][j] = __builtin_amdgcn_mfma_f32_16x16x32_bf16(pa2, bv[j & 3], Oacc[2][j], 0, 0, 0);
        Oacc[3][j] = __builtin_amdgcn_mfma_f32_16x16x32_bf16(pa3, bv[j & 3], Oacc[3][j], 0, 0, 0);
        __builtin_amdgcn_s_setprio(0);
        if (j < 4) {
          bk[j] = ldU(kT, ibe*8 + j + 4);
          bv[j] = ldU(vT, ibe*8 + j + 4);
        } else {
          bk[j - 4] = ldU(kP, ibn*8 + j - 4);
          bv[j - 4] = ldU(vP, ibn*8 + j - 4);
        }
        aqA0 = aqN0; aqA1 = aqN1;
      }
    }
  }

  // ================= epilogue: softmax(15) + PV-only =================
  BAR();
  #pragma unroll
  for (int r = 0; r < 16; ++r) {
    int qrow = (r & 3) + 8*(r >> 2) + 4*sh;
    int s    = w*32 + sl;
    {
      float p = exp2f(qk0[r] * SCL);
      int q = qrow;
      *reinterpret_cast<__bf16*>(plds + q*512 + ((s*2) ^ ((q & 7) << 4))) = (__bf16)p;
    }
    {
      float p = exp2f(qk1[r] * SCL);
      int q = 32 + qrow;
      *reinterpret_cast<__bf16*>(plds + q*512 + ((s*2) ^ ((q & 7) << 4))) = (__bf16)p;
    }
  }
  WAITL();
  BAR();

  {
    const u8* vT = vptr + (size_t)(NT_-1)*524288;
    bf16x8 pa0, pa1, pa2, pa3;
    #pragma unroll 1
    for (int seg = 0; seg < 8; ++seg) {
      const int ibe = (seg + off) & 7;
      const int ibn = (ibe + 1) & 7;
      #pragma unroll
      for (int j = 0; j < 8; ++j) {
        if (j == 0) {
          pa0 = ldP(0, ibe); pa1 = ldP(1, ibe); pa2 = ldP(2, ibe); pa3 = ldP(3, ibe);
          if (ibe == w) {
            lacc[0] = __builtin_amdgcn_mfma_f32_16x16x32_bf16(pa0, ones, lacc[0], 0, 0, 0);
            lacc[1] = __builtin_amdgcn_mfma_f32_16x16x32_bf16(pa1, ones, lacc[1], 0, 0, 0);
            lacc[2] = __builtin_amdgcn_mfma_f32_16x16x32_bf16(pa2, ones, lacc[2], 0, 0, 0);
            lacc[3] = __builtin_amdgcn_mfma_f32_16x16x32_bf16(pa3, ones, lacc[3], 0, 0, 0);
          }
        }
        __builtin_amdgcn_s_setprio(1);
        Oacc[0][j] = __builtin_amdgcn_mfma_f32_16x16x32_bf16(pa0, bv[j & 3], Oacc[0][j], 0, 0, 0);
        Oacc[1][j] = __builtin_amdgcn_mfma_f32_16x16x32_bf16(pa1, bv[j & 3], Oacc[1][j], 0, 0, 0);
        Oacc[2][j] = __builtin_amdgcn_mfma_f32_16x16x32_bf16(pa2, bv[j & 3], Oacc[2][j], 0, 0, 0);
        Oacc[3][j] = __builtin_amdgcn_mfma_f32_16x16x32_bf16(pa3, bv[j & 3], Oacc[3][j], 0, 0, 0);
        __builtin_amdgcn_s_setprio(0);
        if (j < 4)           bv[j] = ldU(vT, ibe*8 + j + 4);
        else if (seg < 7)    bv[j - 4] = ldU(vT, ibn*8 + j - 4);
      }
    }
  }
  BAR();   // all plds reads done

  // ================= l: combine per-wave ones-MFMA partials, write O =================
  float* lred = (float*)plds;
  if (lr == 0) {
    #pragma unroll
    for (int mq = 0; mq < 4; ++mq)
      #pragma unroll
      for (int j = 0; j < 4; ++j)
        lred[w*64 + mq*16 + lg*4 + j] = lacc[mq][j];
  }
  WAITL();
  BAR();

  float* Ob = Og + ((size_t)b*LQ_ + (size_t)qt*BQ_)*DH_;
  #pragma unroll
  for (int mq = 0; mq < 4; ++mq)
    #pragma unroll
    for (int j = 0; j < 4; ++j) {
      int q = mq*16 + lg*4 + j;
      float s = 0.f;
      #pragma unroll
      for (int ww = 0; ww < 8; ++ww) s += lred[ww*64 + q];
      float rinv = 1.0f / s;
      #pragma unroll
      for (int nf = 0; nf < 8; ++nf)
        Ob[(size_t)q*DH_ + w*128 + nf*16 + lr] = Oacc[mq][nf][j] * rinv;
    }
}

// ---------------- correctness-only fallback (ws too small; never expected) ----------------
__global__ void attn_naive(const float* __restrict__ Q, const float* __restrict__ S,
                           float* __restrict__ O)
{
  const int row = blockIdx.x;
  const int b = row >> 12, q = row & 4095;
  const float* qp = Q + ((size_t)b*LQ_ + q)*DH_;
  const float* sp = S + (size_t)b*LS_*DH_;
  __shared__ float qs[DH_];
  __shared__ float osum[DH_];
  __shared__ float lsum;
  for (int i = threadIdx.x; i < DH_; i += 256) { qs[i] = qp[i]; osum[i] = 0.f; }
  if (threadIdx.x == 0) lsum = 0.f;
  __syncthreads();
  float lpart = 0.f;
  for (int s0 = threadIdx.x; s0 < LS_; s0 += 256) {
    const float* sr = sp + (size_t)s0*DH_;
    float dot = 0.f;
    for (int d = 0; d < DH_; ++d) dot += qs[d]*sr[d];
    float p = __expf(dot * 0.03125f);
    lpart += p;
    for (int d = 0; d < DH_; ++d) atomicAdd(&osum[d], p*sr[d]);
  }
  atomicAdd(&lsum, lpart);
  __syncthreads();
  float rinv = 1.0f / lsum;
  float* op = O + ((size_t)b*LQ_ + q)*DH_;
  for (int i = threadIdx.x; i < DH_; i += 256) op[i] = osum[i]*rinv;
}

extern "C" void kernel_launch(void* const* d_in, const int* in_sizes, int n_in,
                              void* d_out, int out_size, void* d_ws, size_t ws_size,
                              hipStream_t stream)
{
  const float* Q = (const float*)d_in[0];
  const float* S = (const float*)d_in[1];
  float* out = (float*)d_out;

  const size_t kf_bytes = (size_t)B_*NT_*8*64*1024;   // 32 MiB (bf16)
  const size_t vf_bytes = (size_t)B_*NT_*8*64*1024;   // 32 MiB (bf16)
  const size_t need = kf_bytes + vf_bytes;            // 64 MiB

  if (ws_size >= need) {
    u8* Kf = (u8*)d_ws;
    u8* Vf = Kf + kf_bytes;
    cvt_kernel<<<dim3(64, 16, 4), 256, 0, stream>>>(S, Kf, Vf);
    attn_kernel<<<dim3(256), NTH, 0, stream>>>(Q, Kf, Vf, out);
  } else {
    attn_naive<<<dim3(B_*LQ_), 256, 0, stream>>>(Q, S, out);
  }
}